// Round 1
// baseline (109.778 us; speedup 1.0000x reference)
//
#include <hip/hip_runtime.h>

#define IN_F 16
#define OUT_F 16
#define EDGE_F 16

// out[n*16+o] = feat[n*16+o] + bias[o], vectorized float4
__global__ __launch_bounds__(256) void init_out_kernel(const float* __restrict__ feat,
                                                       const float* __restrict__ bias,
                                                       float* __restrict__ out,
                                                       int n_elems) {
  int g = blockIdx.x * 256 + threadIdx.x;      // group of 4 floats
  int base = g * 4;
  if (base < n_elems) {
    float4 f = *reinterpret_cast<const float4*>(feat + base);
    const float4* b4 = reinterpret_cast<const float4*>(bias);
    float4 b = b4[g & 3];                      // (base%16)/4
    float4 o;
    o.x = f.x + b.x; o.y = f.y + b.y; o.z = f.z + b.z; o.w = f.w + b.w;
    *reinterpret_cast<float4*>(out + base) = o;
  }
}

__global__ __launch_bounds__(256) void edge_kernel(
    const float* __restrict__ feat, const float* __restrict__ efeat,
    const float* __restrict__ We, const float* __restrict__ be,
    const int* __restrict__ src, const int* __restrict__ dst,
    float* __restrict__ out, int E) {
  int e = blockIdx.x * 256 + threadIdx.x;
  bool valid = (e < E);
  int ec = valid ? e : (E - 1);                // clamp; invalid lanes contribute 0

  int s = src[ec];
  int d = dst[ec];

  // load efeat[e][:] and feat[src[e]][:] as 4x float4
  float ef[16], h[16];
  const float4* e4 = reinterpret_cast<const float4*>(efeat + (size_t)ec * 16);
  const float4* h4 = reinterpret_cast<const float4*>(feat + (size_t)s * 16);
#pragma unroll
  for (int q = 0; q < 4; ++q) {
    float4 t = e4[q];
    ef[q * 4 + 0] = t.x; ef[q * 4 + 1] = t.y; ef[q * 4 + 2] = t.z; ef[q * 4 + 3] = t.w;
    float4 u = h4[q];
    h[q * 4 + 0] = u.x; h[q * 4 + 1] = u.y; h[q * 4 + 2] = u.z; h[q * 4 + 3] = u.w;
  }

  float m[16];
#pragma unroll
  for (int o = 0; o < 16; ++o) m[o] = 0.f;

  // m[o] = sum_i h[i] * ( be[i*16+o] + sum_k ef[k]*We[k*256 + i*16 + o] )
  // i-loop kept rolled (code size ~2KB/iter); We/be indices are wave-uniform -> s_load + SGPR-operand FMA
#pragma unroll 1
  for (int i = 0; i < 16; ++i) {
    float w[16];
#pragma unroll
    for (int o = 0; o < 16; ++o) w[o] = be[i * 16 + o];
#pragma unroll
    for (int k = 0; k < 16; ++k) {
      float efk = ef[k];
#pragma unroll
      for (int o = 0; o < 16; ++o)
        w[o] = fmaf(efk, We[k * 256 + i * 16 + o], w[o]);
    }
    float hi = h[i];
#pragma unroll
    for (int o = 0; o < 16; ++o) m[o] = fmaf(hi, w[o], m[o]);
  }

  if (!valid) {
#pragma unroll
    for (int o = 0; o < 16; ++o) m[o] = 0.f;
  }

  // dst is sorted: wave-level segmented reduction, then one atomic per run-head.
  unsigned lane = threadIdx.x & 63u;
#pragma unroll
  for (int delta = 1; delta < 64; delta <<= 1) {
    int nd = __shfl_down(d, delta, 64);
    bool ok = (lane + delta < 64) && (nd == d);
#pragma unroll
    for (int o = 0; o < 16; ++o) {
      float nv = __shfl_down(m[o], delta, 64);
      if (ok) m[o] += nv;
    }
  }
  int pd = __shfl_up(d, 1, 64);
  bool head = (lane == 0) || (pd != d);

  if (head && valid) {
    float* op = out + (size_t)d * 16;
#pragma unroll
    for (int o = 0; o < 16; ++o) unsafeAtomicAdd(op + o, m[o]);
  }
}

extern "C" void kernel_launch(void* const* d_in, const int* in_sizes, int n_in,
                              void* d_out, int out_size, void* d_ws, size_t ws_size,
                              hipStream_t stream) {
  const float* feat  = (const float*)d_in[0];
  const float* efeat = (const float*)d_in[1];
  const float* We    = (const float*)d_in[2];
  const float* be    = (const float*)d_in[3];
  const float* bias  = (const float*)d_in[4];
  const int*   src   = (const int*)d_in[5];
  const int*   dst   = (const int*)d_in[6];
  float* out = (float*)d_out;

  int E = in_sizes[5];
  int n_elems = out_size;           // 50000*16

  int groups = (n_elems + 3) / 4;
  init_out_kernel<<<(groups + 255) / 256, 256, 0, stream>>>(feat, bias, out, n_elems);
  edge_kernel<<<(E + 255) / 256, 256, 0, stream>>>(feat, efeat, We, be, src, dst, out, E);
}

// Round 2
// 58.476 us; speedup vs baseline: 1.8773x; 1.8773x over previous
//
#include <hip/hip_runtime.h>
#include <hip/hip_bf16.h>

typedef __attribute__((ext_vector_type(8))) short short8v;
typedef __attribute__((ext_vector_type(4))) float f32x4;

#define TPW 8  // 16-edge tiles per wave

// out[n*16+o] = feat[n*16+o] + bias[o]
__global__ __launch_bounds__(256) void init_out_kernel(const float* __restrict__ feat,
                                                       const float* __restrict__ bias,
                                                       float* __restrict__ out,
                                                       int n_elems) {
  int g = blockIdx.x * 256 + threadIdx.x;
  int base = g * 4;
  if (base < n_elems) {
    float4 f = *reinterpret_cast<const float4*>(feat + base);
    const float4* b4 = reinterpret_cast<const float4*>(bias);
    float4 b = b4[g & 3];
    float4 o;
    o.x = f.x + b.x; o.y = f.y + b.y; o.z = f.z + b.z; o.w = f.w + b.w;
    *reinterpret_cast<float4*>(out + base) = o;
  }
}

// Pack Wz (K=288 x N=16) as bf16 into wp, layout [t][g][n][j] so each lane's
// B-fragment for MFMA t is one contiguous 16B load.
// Wz[k][n] = We[(k>>4)*256 + (k&15)*16 + n]   (k < 256)
//          = be[(k-256)*16 + n]               (256 <= k < 272)
//          = 0                                (k >= 272)
__global__ void prep_wz_kernel(const float* __restrict__ We, const float* __restrict__ be,
                               unsigned short* __restrict__ wp) {
  int idx = blockIdx.x * 256 + threadIdx.x;
  if (idx >= 9 * 4 * 16 * 8) return;
  int j = idx & 7, n = (idx >> 3) & 15, g = (idx >> 7) & 3, t = idx >> 9;
  int k = t * 32 + g * 8 + j;
  float v = 0.f;
  if (k < 256) v = We[(k >> 4) * 256 + (k & 15) * 16 + n];
  else if (k < 272) v = be[(k - 256) * 16 + n];
  __hip_bfloat16 b = __float2bfloat16(v);
  wp[idx] = __builtin_bit_cast(unsigned short, b);
}

// Z-GEMM: per wave, 16 edges/tile, K=288 -> 9x mfma_f32_16x16x32_bf16.
// A-frag lane mapping assumed: m = lane&15, k = (lane>>4)*8 + j.
// B-frag: n = lane&15, same k. D: col = lane&15, row = (lane>>4)*4 + r (verified).
__global__ __launch_bounds__(256) void edge_mfma_kernel(
    const float* __restrict__ feat, const float* __restrict__ efeat,
    const int* __restrict__ src, const int* __restrict__ dst,
    const unsigned short* __restrict__ wp,
    float* __restrict__ out, int E) {
  int wave = (blockIdx.x * blockDim.x + threadIdx.x) >> 6;
  int lane = threadIdx.x & 63;
  int g = lane >> 4;
  int m = lane & 15;
  int p = g >> 1;        // ef component parity: Z factor ef[2t+p]
  int hb = (g & 1) * 8;  // h half: h[hb..hb+7]

  // B fragments: persist in registers for the whole kernel (9KB table, L2-hot)
  short8v Bf[9];
#pragma unroll
  for (int t = 0; t < 9; ++t)
    Bf[t] = *reinterpret_cast<const short8v*>(wp + ((size_t)(t * 4 + g) * 16 + m) * 8);

  int tile0 = wave * TPW;
#pragma unroll 1
  for (int tt = 0; tt < TPW; ++tt) {
    int e0 = (tile0 + tt) * 16;
    if (e0 >= E) break;
    int e = e0 + m;

    const float4* efp = reinterpret_cast<const float4*>(efeat + (size_t)e * 16);
    float4 Ea = efp[0], Eb = efp[1], Ec = efp[2], Ed = efp[3];
    int s = src[e];
    const float4* hp = reinterpret_cast<const float4*>(feat + (size_t)s * 16 + hb);
    float4 Ha = hp[0], Hb = hp[1];

    float h[8] = {Ha.x, Ha.y, Ha.z, Ha.w, Hb.x, Hb.y, Hb.z, Hb.w};
    float efs[8];
    efs[0] = p ? Ea.y : Ea.x;  efs[1] = p ? Ea.w : Ea.z;
    efs[2] = p ? Eb.y : Eb.x;  efs[3] = p ? Eb.w : Eb.z;
    efs[4] = p ? Ec.y : Ec.x;  efs[5] = p ? Ec.w : Ec.z;
    efs[6] = p ? Ed.y : Ed.x;  efs[7] = p ? Ed.w : Ed.z;

    f32x4 acc = {0.f, 0.f, 0.f, 0.f};
#pragma unroll
    for (int t = 0; t < 8; ++t) {
      short8v A;
#pragma unroll
      for (int jj = 0; jj < 8; ++jj) {
        float prod = efs[t] * h[jj];                 // fp32 product, single rounding
        __hip_bfloat16 bb = __float2bfloat16(prod);
        A[jj] = __builtin_bit_cast(short, bb);
      }
      acc = __builtin_amdgcn_mfma_f32_16x16x32_bf16(A, Bf[t], acc, 0, 0, 0);
    }
    {  // K-tile 8: be passthrough rows (Z = h[i] at k=256+i), zero pad k>=272
      short8v A;
#pragma unroll
      for (int jj = 0; jj < 8; ++jj) {
        float hv = (g < 2) ? h[jj] : 0.f;
        __hip_bfloat16 bb = __float2bfloat16(hv);
        A[jj] = __builtin_bit_cast(short, bb);
      }
      acc = __builtin_amdgcn_mfma_f32_16x16x32_bf16(A, Bf[8], acc, 0, 0, 0);
    }

    // Lane holds m[e0+g*4+r][m] for r=0..3. dst sorted -> run-combine then atomic.
    int base_e = e0 + g * 4;
    int d0 = dst[base_e + 0], d1 = dst[base_e + 1];
    int d2 = dst[base_e + 2], d3 = dst[base_e + 3];
    float run = acc[0];
    int cur = d0;
    if (d1 == cur) run += acc[1];
    else { unsafeAtomicAdd(out + (size_t)cur * 16 + m, run); cur = d1; run = acc[1]; }
    if (d2 == cur) run += acc[2];
    else { unsafeAtomicAdd(out + (size_t)cur * 16 + m, run); cur = d2; run = acc[2]; }
    if (d3 == cur) run += acc[3];
    else { unsafeAtomicAdd(out + (size_t)cur * 16 + m, run); cur = d3; run = acc[3]; }
    unsafeAtomicAdd(out + (size_t)cur * 16 + m, run);
  }
}

extern "C" void kernel_launch(void* const* d_in, const int* in_sizes, int n_in,
                              void* d_out, int out_size, void* d_ws, size_t ws_size,
                              hipStream_t stream) {
  const float* feat  = (const float*)d_in[0];
  const float* efeat = (const float*)d_in[1];
  const float* We    = (const float*)d_in[2];
  const float* be    = (const float*)d_in[3];
  const float* bias  = (const float*)d_in[4];
  const int*   src   = (const int*)d_in[5];
  const int*   dst   = (const int*)d_in[6];
  float* out = (float*)d_out;

  int E = in_sizes[5];
  int n_elems = out_size;  // 50000*16

  int groups = (n_elems + 3) / 4;
  init_out_kernel<<<(groups + 255) / 256, 256, 0, stream>>>(feat, bias, out, n_elems);
  prep_wz_kernel<<<(9 * 4 * 16 * 8 + 255) / 256, 256, 0, stream>>>(We, be, (unsigned short*)d_ws);

  int tiles = (E + 15) / 16;
  int waves = (tiles + TPW - 1) / TPW;
  int blocks = (waves + 3) / 4;
  edge_mfma_kernel<<<blocks, 256, 0, stream>>>(feat, efeat, src, dst,
                                               (const unsigned short*)d_ws, out, E);
}

// Round 3
// 50.575 us; speedup vs baseline: 2.1706x; 1.1562x over previous
//
#include <hip/hip_runtime.h>
#include <hip/hip_bf16.h>

typedef __attribute__((ext_vector_type(8))) short short8v;
typedef __attribute__((ext_vector_type(4))) float f32x4;

#define TPW 4  // 16-edge tiles per wave

// Fused: out = feat + bias (blocks [0,initB)), Wz bf16 pack (blocks [initB, initB+18))
__global__ __launch_bounds__(256) void setup_kernel(
    const float* __restrict__ feat, const float* __restrict__ bias,
    const float* __restrict__ We, const float* __restrict__ be,
    float* __restrict__ out, unsigned short* __restrict__ wp,
    int n_elems, int initB) {
  if ((int)blockIdx.x < initB) {
    int g = blockIdx.x * 256 + threadIdx.x;
    int base = g * 4;
    if (base < n_elems) {
      float4 f = *reinterpret_cast<const float4*>(feat + base);
      const float4* b4 = reinterpret_cast<const float4*>(bias);
      float4 b = b4[g & 3];
      float4 o;
      o.x = f.x + b.x; o.y = f.y + b.y; o.z = f.z + b.z; o.w = f.w + b.w;
      *reinterpret_cast<float4*>(out + base) = o;
    }
  } else {
    // Wz (K=288 x N=16) bf16, layout [t][g][n][j]:
    // Wz[k][n] = We[(k>>4)*256 + (k&15)*16 + n] (k<256); be[(k-256)*16+n] (k<272); 0 pad
    int idx = (blockIdx.x - initB) * 256 + threadIdx.x;
    if (idx < 9 * 4 * 16 * 8) {
      int j = idx & 7, n = (idx >> 3) & 15, gg = (idx >> 7) & 3, t = idx >> 9;
      int k = t * 32 + gg * 8 + j;
      float v = 0.f;
      if (k < 256) v = We[(k >> 4) * 256 + (k & 15) * 16 + n];
      else if (k < 272) v = be[(k - 256) * 16 + n];
      __hip_bfloat16 b = __float2bfloat16(v);
      wp[idx] = __builtin_bit_cast(unsigned short, b);
    }
  }
}

// Z-GEMM with 1-deep software pipeline across tiles.
// Lane (g = lane>>4, m = lane&15): A-frag m=edge lane, k=(g)*8+j within K-tile;
// Z factor ef[2t + (g>>1)] * h[(g&1)*8 + j].  D: col=lane&15, row=g*4+r.
__global__ __launch_bounds__(256, 4) void edge_mfma_kernel(
    const float* __restrict__ feat, const float* __restrict__ efeat,
    const int* __restrict__ src, const int* __restrict__ dst,
    const unsigned short* __restrict__ wp,
    float* __restrict__ out, int E) {
  int wave = (blockIdx.x * blockDim.x + threadIdx.x) >> 6;
  int lane = threadIdx.x & 63;
  int g = lane >> 4;
  int m = lane & 15;
  int p = g >> 1;        // ef parity
  int hb = (g & 1) * 8;  // h half

  short8v Bf[9];
#pragma unroll
  for (int t = 0; t < 9; ++t)
    Bf[t] = *reinterpret_cast<const short8v*>(wp + ((size_t)(t * 4 + g) * 16 + m) * 8);

  int e0 = wave * TPW * 16;
  if (e0 >= E) return;

  // ---- prologue: loads for tile 0 ----
  float4 Ea, Eb, Ec, Ed, Ha, Hb;
  int4 dd;
  {
    int e = e0 + m;
    const float4* efp = reinterpret_cast<const float4*>(efeat + (size_t)e * 16);
    Ea = efp[0]; Eb = efp[1]; Ec = efp[2]; Ed = efp[3];
    int s = src[e];
    dd = *reinterpret_cast<const int4*>(dst + e0 + g * 4);
    const float4* hp = reinterpret_cast<const float4*>(feat + (size_t)s * 16 + hb);
    Ha = hp[0]; Hb = hp[1];
  }

#pragma unroll
  for (int tt = 0; tt < TPW; ++tt) {
    int e0n = e0 + 16;
    bool hn = (tt < TPW - 1) && (e0n < E);

    // ---- issue next-tile independent loads early ----
    float4 EaN, EbN, EcN, EdN;
    int4 ddN;
    int sN = 0;
    if (hn) {
      int en = e0n + m;
      const float4* efp = reinterpret_cast<const float4*>(efeat + (size_t)en * 16);
      EaN = efp[0]; EbN = efp[1]; EcN = efp[2]; EdN = efp[3];
      sN = src[en];
      ddN = *reinterpret_cast<const int4*>(dst + e0n + g * 4);
    }

    // ---- compute current tile (covers sN latency) ----
    float h[8] = {Ha.x, Ha.y, Ha.z, Ha.w, Hb.x, Hb.y, Hb.z, Hb.w};
    float efs[8];
    efs[0] = p ? Ea.y : Ea.x;  efs[1] = p ? Ea.w : Ea.z;
    efs[2] = p ? Eb.y : Eb.x;  efs[3] = p ? Eb.w : Eb.z;
    efs[4] = p ? Ec.y : Ec.x;  efs[5] = p ? Ec.w : Ec.z;
    efs[6] = p ? Ed.y : Ed.x;  efs[7] = p ? Ed.w : Ed.z;

    f32x4 acc = {0.f, 0.f, 0.f, 0.f};
#pragma unroll
    for (int t = 0; t < 8; ++t) {
      short8v A;
#pragma unroll
      for (int jj = 0; jj < 8; ++jj) {
        float prod = efs[t] * h[jj];            // fp32 product, single rounding
        __hip_bfloat16 bb = __float2bfloat16(prod);
        A[jj] = __builtin_bit_cast(short, bb);
      }
      acc = __builtin_amdgcn_mfma_f32_16x16x32_bf16(A, Bf[t], acc, 0, 0, 0);
    }

    // ---- dependent gather for next tile (sN should have arrived) ----
    float4 HaN, HbN;
    if (hn) {
      const float4* hp = reinterpret_cast<const float4*>(feat + (size_t)sN * 16 + hb);
      HaN = hp[0]; HbN = hp[1];
    }

    {  // K-tile 8: be passthrough (Z = h[i] at k=256+i), zero pad
      short8v A;
#pragma unroll
      for (int jj = 0; jj < 8; ++jj) {
        float hv = (g < 2) ? h[jj] : 0.f;
        __hip_bfloat16 bb = __float2bfloat16(hv);
        A[jj] = __builtin_bit_cast(short, bb);
      }
      acc = __builtin_amdgcn_mfma_f32_16x16x32_bf16(A, Bf[8], acc, 0, 0, 0);
    }

    // ---- epilogue: dst sorted -> run-combine then atomic ----
    {
      float run = acc[0];
      int cur = dd.x;
      if (dd.y == cur) run += acc[1];
      else { unsafeAtomicAdd(out + (size_t)cur * 16 + m, run); cur = dd.y; run = acc[1]; }
      if (dd.z == cur) run += acc[2];
      else { unsafeAtomicAdd(out + (size_t)cur * 16 + m, run); cur = dd.z; run = acc[2]; }
      if (dd.w == cur) run += acc[3];
      else { unsafeAtomicAdd(out + (size_t)cur * 16 + m, run); cur = dd.w; run = acc[3]; }
      unsafeAtomicAdd(out + (size_t)cur * 16 + m, run);
    }

    // ---- rotate ----
    Ea = EaN; Eb = EbN; Ec = EcN; Ed = EdN;
    Ha = HaN; Hb = HbN;
    dd = ddN;
    e0 = e0n;
    if (!hn) break;
  }
}

extern "C" void kernel_launch(void* const* d_in, const int* in_sizes, int n_in,
                              void* d_out, int out_size, void* d_ws, size_t ws_size,
                              hipStream_t stream) {
  const float* feat  = (const float*)d_in[0];
  const float* efeat = (const float*)d_in[1];
  const float* We    = (const float*)d_in[2];
  const float* be    = (const float*)d_in[3];
  const float* bias  = (const float*)d_in[4];
  const int*   src   = (const int*)d_in[5];
  const int*   dst   = (const int*)d_in[6];
  float* out = (float*)d_out;

  int E = in_sizes[5];
  int n_elems = out_size;  // 50000*16

  int groups = (n_elems + 3) / 4;
  int initB = (groups + 255) / 256;
  int prepB = (9 * 4 * 16 * 8 + 255) / 256;
  setup_kernel<<<initB + prepB, 256, 0, stream>>>(feat, bias, We, be, out,
                                                  (unsigned short*)d_ws, n_elems, initB);

  int tiles = (E + 15) / 16;
  int waves = (tiles + TPW - 1) / TPW;
  int blocks = (waves + 3) / 4;
  edge_mfma_kernel<<<blocks, 256, 0, stream>>>(feat, efeat, src, dst,
                                               (const unsigned short*)d_ws, out, E);
}